// Round 16
// baseline (114.668 us; speedup 1.0000x reference)
//
#include <hip/hip_runtime.h>
#include <hip/hip_fp16.h>

#define N_NODES 50000
#define DIM 64
#define CB 391          // buckets = ceil(N/128); bucket = dst >> 7
#define PBLK 131        // partition blocks
#define PEPB 6144       // edges per partition block (512 thr x 12)
#define EPT 12          // edges per thread (register-staged)
#define RUNW 48         // slots per (block,bucket) run = 192 B (mean 15.7, +8 sd)
#define CAPB (PBLK * RUNW)   // 6288 slots per bucket
#define BINCAP 64       // per-node LDS edge slots (deg mean 16 sd 4 -> z=12)
#define PLW 68          // pooled LDS row stride in floats (+4: bank spread)

typedef _Float16 half8 __attribute__((ext_vector_type(8)));
typedef _Float16 half4v __attribute__((ext_vector_type(4)));
typedef float floatx4 __attribute__((ext_vector_type(4)));

// Workspace byte offsets (64B-aligned).
#define WS_COARSE  0                          // CB*CAPB*4 = 9,834,432
#define WS_CNT     9834432                    // PBLK*CB*4 = 204,884 -> 204,928
#define WS_XH      (WS_CNT + 204928)          // N*DIM f16 = 6,400,000
#define WS_WT      (WS_XH + 6400000)          // DIM*DIM f16 = 8,192

// ---------------------------------------------------------------------------
// Prep (one dispatch, 512 thr).  Blocks [0,131): single-pass register-staged
// partition into DETERMINISTIC per-(block,bucket) runs:
//   coarse[bk*6288 + b*48 + r], cnt[b][bk]
// -> no global cursor, no memset, no global atomics; each 192 B run is
// line-aligned and exclusively owned by one block (clean write-combining).
// Blocks [131, 131+1563): x -> fp16.  Last block: W^T fp16.
// Producer->consumer coherence comes from the KERNEL BOUNDARY (R14's
// grid.sync() inside one kernel was insufficient across XCD L2s: absmax 22).
// ---------------------------------------------------------------------------
__global__ void __launch_bounds__(512) prep_kernel(
        const float* __restrict__ x, const float* __restrict__ W,
        const int* __restrict__ edge_src, const int* __restrict__ edge_dst,
        unsigned int* __restrict__ coarse, int* __restrict__ cnt,
        _Float16* __restrict__ xh, _Float16* __restrict__ wt, int E) {
    int b = blockIdx.x, t = threadIdx.x;
    if (b < PBLK) {
        __shared__ int lhist[CB];
        for (int i = t; i < CB; i += 512) lhist[i] = 0;
        __syncthreads();

        int base = b * PEPB;
        unsigned int pk[EPT];
        int bk[EPT];
        #pragma unroll
        for (int j = 0; j < EPT; ++j) {
            int e = base + j * 512 + t;       // coalesced
            bk[j] = -1;
            if (e < E) {
                int s = edge_src[e];
                int d = edge_dst[e];
                bk[j] = d >> 7;
                pk[j] = ((unsigned int)s << 7) | (unsigned int)(d & 127);
                atomicAdd(&lhist[bk[j]], 1);
            }
        }
        __syncthreads();
        for (int i = t; i < CB; i += 512) {
            cnt[(size_t)b * CB + i] = lhist[i];
            lhist[i] = 0;                     // reuse as running cursor
        }
        __syncthreads();
        #pragma unroll
        for (int j = 0; j < EPT; ++j) {
            if (bk[j] >= 0) {
                int r = atomicAdd(&lhist[bk[j]], 1);
                coarse[(size_t)bk[j] * CAPB + b * RUNW + r] = pk[j];
            }
        }
    } else if (b < PBLK + 1563) {
        int i = (b - PBLK) * 512 + t;         // one float4 per thread
        if (i < N_NODES * DIM / 4) {
            float4 v = reinterpret_cast<const float4*>(x)[i];
            half4v h = { (_Float16)v.x, (_Float16)v.y, (_Float16)v.z, (_Float16)v.w };
            reinterpret_cast<half4v*>(xh)[i] = h;
        }
    } else {
        #pragma unroll
        for (int i = 0; i < 8; ++i) {         // W^T: wt[n*64+k] = W[k*64+n]
            int idx = t * 8 + i;
            int n = idx >> 6, k = idx & 63;
            wt[idx] = (_Float16)W[k * DIM + n];
        }
    }
}

// ---------------------------------------------------------------------------
// Fused bin + gather + project (== R13 structure + ushort sedges + run-based
// scatter).  Grid 784; block b = half (b>>3)&1 of bucket (b>>4)*8+(b&7)
// (sibling pair (b,b^8) -> same XCD under round-robin dispatch).
//  1. lane i<131 streams run i of the bucket, dropping matching edges into
//     per-node slot arrays (ushort sedges[bin*64+slot], LDS atomic slot).
//  2. 32 groups x 8 lanes, 2 nodes/group: 8 edges in flight, half8 fp16
//     gather, fp32 register accumulate, residual from xh (L2-hot), one
//     ds_write per row chunk into the stride-68 fp32 tile.
//  3. 4 waves x 16 nodes: fp32->f16 A-frags from tile, B-frags from W^T,
//     2x mfma_f32_16x16x32_f16 per N-tile, bias + /deg + ReLU -> out.
// ---------------------------------------------------------------------------
__global__ void __launch_bounds__(256) fused_kernel(
        const _Float16* __restrict__ xh,
        const _Float16* __restrict__ wt,
        const float* __restrict__ bias,
        const float* __restrict__ deg,
        const int* __restrict__ cnt,
        const unsigned int* __restrict__ coarse,
        float* __restrict__ out) {
    __shared__ unsigned short sedges[64 * BINCAP];   // 8 KB
    __shared__ float pl[64 * PLW];                   // 17.4 KB
    __shared__ int cur[64];

    int t = threadIdx.x;
    int b = blockIdx.x;
    int bucket = (b >> 4) * 8 + (b & 7);   // sibling pair (b, b^8) same XCD
    int half = (b >> 3) & 1;
    if (bucket >= CB) return;              // block-uniform early-out
    int nb = bucket * 128 + half * 64;

    if (t < 64) cur[t] = 0;
    __syncthreads();

    // --- 1. binned scatter from the 131 runs (lane i owns run i) ---
    if (t < PBLK) {
        int ci = cnt[(size_t)t * CB + bucket];
        const unsigned int* rp = coarse + (size_t)bucket * CAPB + t * RUNW;
        for (int r = 0; r < ci; ++r) {
            unsigned int e = rp[r];
            int loc = (int)(e & 127u);
            if ((loc >> 6) == half) {
                int bin = loc & 63;
                int p = atomicAdd(&cur[bin], 1);
                sedges[bin * BINCAP + p] = (unsigned short)(e >> 7);
            }
        }
    }
    __syncthreads();

    // --- 2. gather: 32 groups of 8 lanes, 2 nodes per group, 8 in flight ---
    int g = t >> 3;
    int c = t & 7;
    #pragma unroll
    for (int pass = 0; pass < 2; ++pass) {
        int loc = g + pass * 32;
        int node = nb + loc;
        float acc[8];
        #pragma unroll
        for (int j = 0; j < 8; ++j) acc[j] = 0.f;
        const unsigned short* bp = &sedges[loc * BINCAP];
        int ct = cur[loc];
        int k = 0;
        for (; k + 8 <= ct; k += 8) {
            int sid[8];
            #pragma unroll
            for (int u = 0; u < 8; ++u) sid[u] = (int)bp[k + u];
            half8 v[8];
            #pragma unroll
            for (int u = 0; u < 8; ++u)
                v[u] = *reinterpret_cast<const half8*>(xh + (size_t)sid[u] * DIM + c * 8);
            #pragma unroll
            for (int u = 0; u < 8; ++u) {
                #pragma unroll
                for (int j = 0; j < 8; ++j) acc[j] += (float)v[u][j];
            }
        }
        for (; k + 4 <= ct; k += 4) {
            int sid[4];
            #pragma unroll
            for (int u = 0; u < 4; ++u) sid[u] = (int)bp[k + u];
            half8 v[4];
            #pragma unroll
            for (int u = 0; u < 4; ++u)
                v[u] = *reinterpret_cast<const half8*>(xh + (size_t)sid[u] * DIM + c * 8);
            #pragma unroll
            for (int u = 0; u < 4; ++u) {
                #pragma unroll
                for (int j = 0; j < 8; ++j) acc[j] += (float)v[u][j];
            }
        }
        for (; k < ct; ++k) {
            int s0 = (int)bp[k];
            half8 v0 = *reinterpret_cast<const half8*>(xh + (size_t)s0 * DIM + c * 8);
            #pragma unroll
            for (int j = 0; j < 8; ++j) acc[j] += (float)v0[j];
        }
        if (node < N_NODES) {
            half8 r = *reinterpret_cast<const half8*>(xh + (size_t)node * DIM + c * 8);
            float* p = &pl[loc * PLW + c * 8];
            #pragma unroll
            for (int j = 0; j < 8; ++j) p[j] = acc[j] + (float)r[j];
        }
    }
    __syncthreads();

    // --- 3. MFMA projection: wave wv handles nodes lbase..lbase+15 ---
    int wv = t >> 6;
    int lane = t & 63;
    int m = lane & 15;
    int q = lane >> 4;
    int lbase = wv * 16;

    const float* ap = &pl[(lbase + m) * PLW];
    half8 a0, a1;
    #pragma unroll
    for (int j = 0; j < 8; ++j) a0[j] = (_Float16)ap[q * 8 + j];
    #pragma unroll
    for (int j = 0; j < 8; ++j) a1[j] = (_Float16)ap[32 + q * 8 + j];

    floatx4 acc4[4];
    #pragma unroll
    for (int tt = 0; tt < 4; ++tt) {
        half8 b0 = *reinterpret_cast<const half8*>(wt + (size_t)(tt * 16 + m) * DIM + q * 8);
        half8 b1 = *reinterpret_cast<const half8*>(wt + (size_t)(tt * 16 + m) * DIM + q * 8 + 32);
        floatx4 cfrag = {0.f, 0.f, 0.f, 0.f};
        cfrag = __builtin_amdgcn_mfma_f32_16x16x32_f16(a0, b0, cfrag, 0, 0, 0);
        cfrag = __builtin_amdgcn_mfma_f32_16x16x32_f16(a1, b1, cfrag, 0, 0, 0);
        acc4[tt] = cfrag;
    }

    #pragma unroll
    for (int r = 0; r < 4; ++r) {
        int row = q * 4 + r;
        int node = nb + lbase + row;
        if (node < N_NODES) {
            float inv = 1.0f / deg[node];
            #pragma unroll
            for (int tt = 0; tt < 4; ++tt) {
                float v = (acc4[tt][r] + bias[tt * 16 + m]) * inv;
                out[(size_t)node * DIM + tt * 16 + m] = fmaxf(v, 0.f);
            }
        }
    }
}

extern "C" void kernel_launch(void* const* d_in, const int* in_sizes, int n_in,
                              void* d_out, int out_size, void* d_ws, size_t ws_size,
                              hipStream_t stream) {
    const float* x        = (const float*)d_in[0];
    const float* weight   = (const float*)d_in[1];
    const float* bias     = (const float*)d_in[2];
    const float* node_deg = (const float*)d_in[3];
    const int*   edge_src = (const int*)d_in[4];
    const int*   edge_dst = (const int*)d_in[5];
    float* out = (float*)d_out;
    int E = in_sizes[4];

    char* ws = (char*)d_ws;
    unsigned int* coarse = (unsigned int*)(ws + WS_COARSE);
    int*          cnt    = (int*)(ws + WS_CNT);
    _Float16*     xh     = (_Float16*)(ws + WS_XH);
    _Float16*     wt     = (_Float16*)(ws + WS_WT);

    prep_kernel<<<PBLK + 1563 + 1, 512, 0, stream>>>(
        x, weight, edge_src, edge_dst, coarse, cnt, xh, wt, E);

    fused_kernel<<<784, 256, 0, stream>>>(
        xh, wt, bias, node_deg, cnt, coarse, out);
}

// Round 17
// 112.369 us; speedup vs baseline: 1.0205x; 1.0205x over previous
//
#include <hip/hip_runtime.h>
#include <hip/hip_fp16.h>

#define N_NODES 50000
#define DIM 64
#define CB 391          // buckets = ceil(N/128); bucket = dst >> 7
#define PBLK 131        // partition blocks
#define PEPB 6144       // edges per partition block (512 thr x 12)
#define EPT 12          // edges per thread (register-staged)
#define RUNW 48         // slots per (block,bucket) run = 192 B (mean 15.7, +8 sd)
#define CAPB (PBLK * RUNW)   // 6288 slots per bucket
#define BINCAP 64       // per-node LDS edge slots (deg mean 16 sd 4 -> z=12)
#define PLW 68          // pooled LDS row stride in floats (+4: bank spread)

typedef _Float16 half8 __attribute__((ext_vector_type(8)));
typedef _Float16 half4v __attribute__((ext_vector_type(4)));
typedef float floatx4 __attribute__((ext_vector_type(4)));

// Workspace byte offsets (64B-aligned).
#define WS_COARSE  0                          // CB*CAPB*4 = 9,834,432
#define WS_CNT     9834432                    // PBLK*CB*4 = 204,884 -> 204,928
#define WS_XH      (WS_CNT + 204928)          // N*DIM f16 = 6,400,000
#define WS_WT      (WS_XH + 6400000)          // DIM*DIM f16 = 8,192

// ---------------------------------------------------------------------------
// Prep (one dispatch, 512 thr, == R15).  Blocks [0,131): single-pass
// register-staged partition into DETERMINISTIC per-(block,bucket) runs:
//   coarse[bk*6288 + b*48 + r], cnt[b][bk]
// -> no global cursor, no memset, no global atomics.  Blocks [131,1694):
// x -> fp16.  Last block: W^T fp16.  Producer->consumer coherence via the
// KERNEL BOUNDARY (grid.sync() inside one kernel is NOT sufficient across
// XCD L2s — R14 failed with absmax 22).
// ---------------------------------------------------------------------------
__global__ void __launch_bounds__(512) prep_kernel(
        const float* __restrict__ x, const float* __restrict__ W,
        const int* __restrict__ edge_src, const int* __restrict__ edge_dst,
        unsigned int* __restrict__ coarse, int* __restrict__ cnt,
        _Float16* __restrict__ xh, _Float16* __restrict__ wt, int E) {
    int b = blockIdx.x, t = threadIdx.x;
    if (b < PBLK) {
        __shared__ int lhist[CB];
        for (int i = t; i < CB; i += 512) lhist[i] = 0;
        __syncthreads();

        int base = b * PEPB;
        unsigned int pk[EPT];
        int bk[EPT];
        #pragma unroll
        for (int j = 0; j < EPT; ++j) {
            int e = base + j * 512 + t;       // coalesced
            bk[j] = -1;
            if (e < E) {
                int s = edge_src[e];
                int d = edge_dst[e];
                bk[j] = d >> 7;
                pk[j] = ((unsigned int)s << 7) | (unsigned int)(d & 127);
                atomicAdd(&lhist[bk[j]], 1);
            }
        }
        __syncthreads();
        for (int i = t; i < CB; i += 512) {
            cnt[(size_t)b * CB + i] = lhist[i];
            lhist[i] = 0;                     // reuse as running cursor
        }
        __syncthreads();
        #pragma unroll
        for (int j = 0; j < EPT; ++j) {
            if (bk[j] >= 0) {
                int r = atomicAdd(&lhist[bk[j]], 1);
                coarse[(size_t)bk[j] * CAPB + b * RUNW + r] = pk[j];
            }
        }
    } else if (b < PBLK + 1563) {
        int i = (b - PBLK) * 512 + t;         // one float4 per thread
        if (i < N_NODES * DIM / 4) {
            float4 v = reinterpret_cast<const float4*>(x)[i];
            half4v h = { (_Float16)v.x, (_Float16)v.y, (_Float16)v.z, (_Float16)v.w };
            reinterpret_cast<half4v*>(xh)[i] = h;
        }
    } else {
        #pragma unroll
        for (int i = 0; i < 8; ++i) {         // W^T: wt[n*64+k] = W[k*64+n]
            int idx = t * 8 + i;
            int n = idx >> 6, k = idx & 63;
            wt[idx] = (_Float16)W[k * DIM + n];
        }
    }
}

// ---------------------------------------------------------------------------
// Fused bin + gather + project — ONE 512-thread block per 128-node bucket
// (grid 391; ~52 KB LDS -> 3 blocks/CU, 768 >= 391 so all co-resident).
// Each bucket's edge list is scanned ONCE (R13/R15 scanned it twice):
//  1. lcnt[131] staged in LDS; coalesced strided scan over the 6288 slots
//     (validity r < lcnt[run]); matching edges drop into per-node ushort
//     slot arrays via LDS atomic.
//  2. 64 groups x 8 lanes, 2 nodes/group: 8 edges in flight, half8 fp16
//     gather, fp32 register accumulate, residual from xh (L2-hot), one
//     ds_write per row chunk into the stride-68 fp32 tile.
//  3. 8 waves x 16 nodes: fp32->f16 A-frags from tile, B-frags from W^T,
//     2x mfma_f32_16x16x32_f16 per N-tile, bias + /deg + ReLU -> out.
// ---------------------------------------------------------------------------
__global__ void __launch_bounds__(512) fused_kernel(
        const _Float16* __restrict__ xh,
        const _Float16* __restrict__ wt,
        const float* __restrict__ bias,
        const float* __restrict__ deg,
        const int* __restrict__ cnt,
        const unsigned int* __restrict__ coarse,
        float* __restrict__ out) {
    __shared__ unsigned short sedges[128 * BINCAP];  // 16 KB
    __shared__ float pl[128 * PLW];                  // 34.8 KB
    __shared__ int cur[128];
    __shared__ int lcnt[PBLK];

    int t = threadIdx.x;
    int bucket = blockIdx.x;
    int nb = bucket * 128;

    if (t < 128) cur[t] = 0;
    if (t >= 128 && t < 128 + PBLK)
        lcnt[t - 128] = cnt[(size_t)(t - 128) * CB + bucket];
    __syncthreads();

    // --- 1. single coalesced scan over the bucket's 131 runs ---
    const unsigned int* cbk = coarse + (size_t)bucket * CAPB;
    for (int i = t; i < CAPB; i += 512) {
        int run = i / RUNW;                 // magic-multiply by compiler
        int r = i - run * RUNW;
        if (r < lcnt[run]) {
            unsigned int e = cbk[i];
            int loc = (int)(e & 127u);
            int p = atomicAdd(&cur[loc], 1);
            sedges[loc * BINCAP + p] = (unsigned short)(e >> 7);
        }
    }
    __syncthreads();

    // --- 2. gather: 64 groups of 8 lanes, 2 nodes per group, 8 in flight ---
    int g = t >> 3;          // group 0..63
    int c = t & 7;           // half8 chunk within the row
    #pragma unroll
    for (int pass = 0; pass < 2; ++pass) {
        int loc = g + pass * 64;
        int node = nb + loc;
        float acc[8];
        #pragma unroll
        for (int j = 0; j < 8; ++j) acc[j] = 0.f;
        const unsigned short* bp = &sedges[loc * BINCAP];
        int ct = cur[loc];                  // 0 for nodes >= N (no edges)
        int k = 0;
        for (; k + 8 <= ct; k += 8) {
            int sid[8];
            #pragma unroll
            for (int u = 0; u < 8; ++u) sid[u] = (int)bp[k + u];
            half8 v[8];
            #pragma unroll
            for (int u = 0; u < 8; ++u)
                v[u] = *reinterpret_cast<const half8*>(xh + (size_t)sid[u] * DIM + c * 8);
            #pragma unroll
            for (int u = 0; u < 8; ++u) {
                #pragma unroll
                for (int j = 0; j < 8; ++j) acc[j] += (float)v[u][j];
            }
        }
        for (; k + 4 <= ct; k += 4) {
            int sid[4];
            #pragma unroll
            for (int u = 0; u < 4; ++u) sid[u] = (int)bp[k + u];
            half8 v[4];
            #pragma unroll
            for (int u = 0; u < 4; ++u)
                v[u] = *reinterpret_cast<const half8*>(xh + (size_t)sid[u] * DIM + c * 8);
            #pragma unroll
            for (int u = 0; u < 4; ++u) {
                #pragma unroll
                for (int j = 0; j < 8; ++j) acc[j] += (float)v[u][j];
            }
        }
        for (; k < ct; ++k) {
            int s0 = (int)bp[k];
            half8 v0 = *reinterpret_cast<const half8*>(xh + (size_t)s0 * DIM + c * 8);
            #pragma unroll
            for (int j = 0; j < 8; ++j) acc[j] += (float)v0[j];
        }
        if (node < N_NODES) {
            half8 r = *reinterpret_cast<const half8*>(xh + (size_t)node * DIM + c * 8);
            float* p = &pl[loc * PLW + c * 8];
            #pragma unroll
            for (int j = 0; j < 8; ++j) p[j] = acc[j] + (float)r[j];
        }
    }
    __syncthreads();

    // --- 3. MFMA projection: wave wv (0..7) handles nodes lbase..lbase+15 ---
    int wv = t >> 6;
    int lane = t & 63;
    int m = lane & 15;
    int q = lane >> 4;
    int lbase = wv * 16;

    const float* ap = &pl[(lbase + m) * PLW];
    half8 a0, a1;
    #pragma unroll
    for (int j = 0; j < 8; ++j) a0[j] = (_Float16)ap[q * 8 + j];
    #pragma unroll
    for (int j = 0; j < 8; ++j) a1[j] = (_Float16)ap[32 + q * 8 + j];

    floatx4 acc4[4];
    #pragma unroll
    for (int tt = 0; tt < 4; ++tt) {
        half8 b0 = *reinterpret_cast<const half8*>(wt + (size_t)(tt * 16 + m) * DIM + q * 8);
        half8 b1 = *reinterpret_cast<const half8*>(wt + (size_t)(tt * 16 + m) * DIM + q * 8 + 32);
        floatx4 cfrag = {0.f, 0.f, 0.f, 0.f};
        cfrag = __builtin_amdgcn_mfma_f32_16x16x32_f16(a0, b0, cfrag, 0, 0, 0);
        cfrag = __builtin_amdgcn_mfma_f32_16x16x32_f16(a1, b1, cfrag, 0, 0, 0);
        acc4[tt] = cfrag;
    }

    #pragma unroll
    for (int r = 0; r < 4; ++r) {
        int row = q * 4 + r;
        int node = nb + lbase + row;
        if (node < N_NODES) {
            float inv = 1.0f / deg[node];
            #pragma unroll
            for (int tt = 0; tt < 4; ++tt) {
                float v = (acc4[tt][r] + bias[tt * 16 + m]) * inv;
                out[(size_t)node * DIM + tt * 16 + m] = fmaxf(v, 0.f);
            }
        }
    }
}

extern "C" void kernel_launch(void* const* d_in, const int* in_sizes, int n_in,
                              void* d_out, int out_size, void* d_ws, size_t ws_size,
                              hipStream_t stream) {
    const float* x        = (const float*)d_in[0];
    const float* weight   = (const float*)d_in[1];
    const float* bias     = (const float*)d_in[2];
    const float* node_deg = (const float*)d_in[3];
    const int*   edge_src = (const int*)d_in[4];
    const int*   edge_dst = (const int*)d_in[5];
    float* out = (float*)d_out;
    int E = in_sizes[4];

    char* ws = (char*)d_ws;
    unsigned int* coarse = (unsigned int*)(ws + WS_COARSE);
    int*          cnt    = (int*)(ws + WS_CNT);
    _Float16*     xh     = (_Float16*)(ws + WS_XH);
    _Float16*     wt     = (_Float16*)(ws + WS_WT);

    prep_kernel<<<PBLK + 1563 + 1, 512, 0, stream>>>(
        x, weight, edge_src, edge_dst, coarse, cnt, xh, wt, E);

    fused_kernel<<<CB, 512, 0, stream>>>(
        xh, wt, bias, node_deg, cnt, coarse, out);
}